// Round 6
// baseline (383.753 us; speedup 1.0000x reference)
//
#include <hip/hip_runtime.h>

#define NN 50000
#define EE 800000
#define RR 8
#define DD 128
#define SS (NN*RR)        // 400000 segments (dst*8 + rel)
#define TE (2*EE)         // 1600000 directed edges
#define SCB 391           // scan blocks: ceil(SS/1024)

typedef __attribute__((ext_vector_type(8))) short bf16x8;
typedef __attribute__((ext_vector_type(4))) float f32x4;

__device__ __forceinline__ unsigned short f2bf(float f){
  unsigned int u = __float_as_uint(f);
  u += 0x7fffu + ((u >> 16) & 1u);   // round-to-nearest-even
  return (unsigned short)(u >> 16);
}
__device__ __forceinline__ float bf_lo(unsigned int w){ return __uint_as_float(w << 16); }
__device__ __forceinline__ float bf_hi(unsigned int w){ return __uint_as_float(w & 0xffff0000u); }

__device__ __forceinline__ void acc8(float* a, uint4 u){
  a[0] += bf_lo(u.x); a[1] += bf_hi(u.x);
  a[2] += bf_lo(u.y); a[3] += bf_hi(u.y);
  a[4] += bf_lo(u.z); a[5] += bf_hi(u.z);
  a[6] += bf_lo(u.w); a[7] += bf_hi(u.w);
}
__device__ __forceinline__ void acc8s(float* a, uint4 u, float s){
  a[0] += s*bf_lo(u.x); a[1] += s*bf_hi(u.x);
  a[2] += s*bf_lo(u.y); a[3] += s*bf_hi(u.y);
  a[4] += s*bf_lo(u.z); a[5] += s*bf_hi(u.z);
  a[6] += s*bf_lo(u.w); a[7] += s*bf_hi(u.w);
}

// directed edge j in [0,TE): j<EE forward (s->d), else reversed
__device__ __forceinline__ void dir_edge(const int* ei, const int* et, int j,
                                         int& s, int& d, int& t){
  if (j < EE){ s = ei[j]; d = ei[EE + j]; t = et[j]; }
  else { int jj = j - EE; s = ei[EE + jj]; d = ei[jj]; t = et[jj]; }
}

// ===========================================================================
// PREP: direct counting sort over 400K (dst,rel) segments
//   memset(deg=0) -> k_deg (global atomics) -> scan (3 kernels) -> k_place
// ===========================================================================

__global__ __launch_bounds__(256) void k_deg(const int* __restrict__ ei,
                                             const int* __restrict__ et,
                                             int* __restrict__ deg){
  for (int j = blockIdx.x*256 + threadIdx.x; j < TE; j += gridDim.x*256){
    int s, d, t; dir_edge(ei, et, j, s, d, t);
    atomicAdd(&deg[d*8 + t], 1);
  }
}

// block-level exclusive scan of deg -> offs (partial) + blksum
__global__ __launch_bounds__(256) void k_scan1(const int* __restrict__ deg,
                                               int* __restrict__ offs,
                                               int* __restrict__ blksum){
  __shared__ int sd[256];
  int b = blockIdx.x, tid = threadIdx.x;
  int base = b*1024 + tid*4;
  int v0 = (base+0 < SS) ? deg[base+0] : 0;
  int v1 = (base+1 < SS) ? deg[base+1] : 0;
  int v2 = (base+2 < SS) ? deg[base+2] : 0;
  int v3 = (base+3 < SS) ? deg[base+3] : 0;
  int ts = v0+v1+v2+v3;
  sd[tid] = ts; __syncthreads();
  for (int o = 1; o < 256; o <<= 1){
    int t = (tid >= o) ? sd[tid-o] : 0;
    __syncthreads();
    sd[tid] += t;
    __syncthreads();
  }
  int ex = sd[tid] - ts;
  if (base+0 < SS) offs[base+0] = ex; ex += v0;
  if (base+1 < SS) offs[base+1] = ex; ex += v1;
  if (base+2 < SS) offs[base+2] = ex; ex += v2;
  if (base+3 < SS) offs[base+3] = ex;
  if (tid == 255) blksum[b] = sd[255];
}

__global__ __launch_bounds__(512) void k_scan2(int* __restrict__ blksum, int nb){
  __shared__ int sd[512];
  int tid = threadIdx.x;
  int v = (tid < nb) ? blksum[tid] : 0;
  sd[tid] = v; __syncthreads();
  for (int o = 1; o < 512; o <<= 1){
    int t = (tid >= o) ? sd[tid-o] : 0;
    __syncthreads();
    sd[tid] += t;
    __syncthreads();
  }
  if (tid < nb) blksum[tid] = sd[tid] - v;   // exclusive
}

// finalize offs; also copy to cur (atomic cursors) and write sentinel
__global__ __launch_bounds__(256) void k_scan3(int* __restrict__ offs,
                                               int* __restrict__ cur,
                                               const int* __restrict__ blksum){
  int i = blockIdx.x*blockDim.x + threadIdx.x;
  if (i < SS){
    int v = offs[i] + blksum[i >> 10];
    offs[i] = v;
    cur[i] = v;
  }
  if (i == 0) offs[SS] = TE;
}

// esrc entries packed: src (17b) | rel (3b @17)
__global__ __launch_bounds__(256) void k_place(const int* __restrict__ ei,
                                               const int* __restrict__ et,
                                               int* __restrict__ cur,
                                               int* __restrict__ esrc){
  for (int j = blockIdx.x*256 + threadIdx.x; j < TE; j += gridDim.x*256){
    int s, d, t; dir_edge(ei, et, j, s, d, t);
    int p = atomicAdd(&cur[d*8 + t], 1);
    esrc[p] = s | (t << 17);
  }
}

// ---- merged conversions: x->bf16, W/self_W -> bf16 transposed -------------
__global__ __launch_bounds__(256) void k_conv(const float* __restrict__ x,
                                              const float* __restrict__ w,
                                              const float* __restrict__ sw,
                                              unsigned short* __restrict__ xb,
                                              unsigned short* __restrict__ wb){
  int i = blockIdx.x*blockDim.x + threadIdx.x;
  const int M1 = NN*DD/4;            // 1,600,000 float4 groups
  if (i < M1){
    float4 v = ((const float4*)x)[i];
    ushort4 o;
    o.x = f2bf(v.x); o.y = f2bf(v.y); o.z = f2bf(v.z); o.w = f2bf(v.w);
    ((ushort4*)xb)[i] = o;
  } else {
    int j = i - M1;
    if (j < 9*DD*DD){
      int r = j >> 14; int rem = j & 16383; int n = rem >> 7; int k = rem & 127;
      float v = (r < 8) ? w[r*16384 + k*128 + n] : sw[k*128 + n];
      wb[j] = f2bf(v);
    }
  }
}

// ===========================================================================
// k_xw: xw[r] = xb @ W_r, r = 0..8 — m97-structure GEMM.
// Block = 256 thr (4 waves), M-tile 128 rows, full N=128, 9 B panels.
// B panel (32 KB) staged to LDS once per block per rel via global_load_lds
// (width 16), double-buffered, stage(r+1) issued before compute(r).
// LDS XOR-swizzle: source pre-swizzled (chunk ^ n&7), ds_read applies same
// XOR -> conflict-free b128 reads (G4 / m173 pattern).
// ===========================================================================
__global__ __launch_bounds__(256, 2) void k_xw(
    const unsigned short* __restrict__ xb,
    const unsigned short* __restrict__ wb,
    unsigned short* __restrict__ xw)
{
  __shared__ __align__(16) unsigned short Bs[2][128*128];   // 2 x 32 KiB
  const int tid  = threadIdx.x;
  const int wave = tid >> 6, lane = tid & 63;
  const int l15  = lane & 15, quad = lane >> 4;
  const int row0 = blockIdx.x * 128 + wave * 32;

  // A fragments: 2 m-tiles x 4 k-slices, loaded once, reused for all 9 rels
  bf16x8 af[2][4];
  #pragma unroll
  for (int m = 0; m < 2; ++m){
    int gr = row0 + m*16 + l15; if (gr >= NN) gr = NN - 1;
    #pragma unroll
    for (int ks = 0; ks < 4; ++ks)
      af[m][ks] = *(const bf16x8*)(xb + (size_t)gr*DD + ks*32 + quad*8);
  }

  // stage panel r into buffer b: 8 calls x (64 lanes x 16 B) per wave
  auto stage = [&](int r, int b){
    #pragma unroll
    for (int j = 0; j < 8; ++j){
      int n = j*16 + wave*4 + (lane >> 4);       // B row 0..127
      int c = lane & 15;                         // 16B chunk within row
      const unsigned short* gp = wb + r*16384 + n*128 + ((c ^ (n & 7)) << 3);
      __builtin_amdgcn_global_load_lds(
          (const __attribute__((address_space(1))) void*)gp,
          (__attribute__((address_space(3))) void*)((char*)&Bs[b][0] + j*4096 + wave*1024),
          16, 0, 0);
    }
  };

  stage(0, 0);

  #pragma unroll 1
  for (int r = 0; r < 9; ++r){
    __syncthreads();                   // stage(r) complete; buf[(r-1)&1] free
    if (r < 8) stage(r + 1, (r + 1) & 1);

    f32x4 C[2][8];
    #pragma unroll
    for (int m = 0; m < 2; ++m)
      #pragma unroll
      for (int nt = 0; nt < 8; ++nt) C[m][nt] = (f32x4)(0.f);

    const char* bb = (const char*)&Bs[r & 1][0];
    #pragma unroll
    for (int nt = 0; nt < 8; ++nt){
      bf16x8 bf[4];
      #pragma unroll
      for (int ks = 0; ks < 4; ++ks)
        bf[ks] = *(const bf16x8*)(bb + (nt*16 + l15)*256
                                     + (((ks*4 + quad) ^ (l15 & 7)) << 4));
      #pragma unroll
      for (int ks = 0; ks < 4; ++ks){
        C[0][nt] = __builtin_amdgcn_mfma_f32_16x16x32_bf16(af[0][ks], bf[ks], C[0][nt], 0, 0, 0);
        C[1][nt] = __builtin_amdgcn_mfma_f32_16x16x32_bf16(af[1][ks], bf[ks], C[1][nt], 0, 0, 0);
      }
    }

    unsigned short* xs = xw + (size_t)r * NN * DD;
    #pragma unroll
    for (int m = 0; m < 2; ++m)
      #pragma unroll
      for (int nt = 0; nt < 8; ++nt)
        #pragma unroll
        for (int i = 0; i < 4; ++i){
          int gr = row0 + m*16 + quad*4 + i;
          if (gr < NN) xs[(size_t)gr*DD + nt*16 + l15] = f2bf(C[m][nt][i]);
        }
  }
}

// ===========================================================================
// k_agg: out[d] = sum_edges (1/deg_seg)*xw[rel][src] + xw[8][d]
// 16-lane group per dst. pk (edge records) prefetched one batch ahead so the
// esrc -> shfl -> row-load chain is pipelined; 8 row-loads in flight/lane.
// ===========================================================================
__global__ __launch_bounds__(256, 4) void k_agg(
    const unsigned short* __restrict__ xw,
    const int* __restrict__ offs,
    const int* __restrict__ esrc,
    float* __restrict__ out)
{
  const int tid   = threadIdx.x;
  const int lane  = tid & 63;
  const int gl    = lane & 15;
  const int basel = lane & 48;               // group base lane within wave
  const int d     = blockIdx.x * 16 + (tid >> 4);   // NN = 3125*16 exact

  int o = 0;
  if (gl < 9) o = offs[d*8 + gl];
  int onx = __shfl(o, (basel + gl + 1) & 63);       // valid for gl<8
  int cnt = onx - o;
  float scale = (gl < 8 && cnt > 0) ? 1.0f/(float)cnt : 0.0f;
  int ebase = __shfl(o, basel);
  int etot  = __shfl(o, basel + 8) - ebase;

  float a[8] = {0.f,0.f,0.f,0.f,0.f,0.f,0.f,0.f};

  int pk[8];
  #pragma unroll
  for (int s = 0; s < 8; ++s) pk[s] = (s < etot) ? esrc[ebase + s] : 0;

  for (int e = 0; e < etot; e += 8){
    uint4 U[8]; float sc[8];
    #pragma unroll
    for (int s = 0; s < 8; ++s){
      sc[s] = 0.f;
      U[s] = make_uint4(0u,0u,0u,0u);
      if (e + s < etot){
        int rel = (pk[s] >> 17) & 7;
        sc[s]   = __shfl(scale, basel + rel);
        int src = pk[s] & 0x1ffff;
        U[s] = *(const uint4*)(xw + ((size_t)rel*NN + src)*DD + gl*8);
      }
    }
    #pragma unroll
    for (int s = 0; s < 8; ++s){              // prefetch next batch's records
      int en = e + 8 + s;
      pk[s] = (en < etot) ? esrc[ebase + en] : 0;
    }
    #pragma unroll
    for (int s = 0; s < 8; ++s) acc8s(a, U[s], sc[s]);
  }

  // self row (slab 8), scale 1
  {
    uint4 u = *(const uint4*)(xw + ((size_t)8*NN + d)*DD + gl*8);
    acc8(a, u);
  }

  float4 v0; v0.x = a[0]; v0.y = a[1]; v0.z = a[2]; v0.w = a[3];
  float4 v1; v1.x = a[4]; v1.y = a[5]; v1.z = a[6]; v1.w = a[7];
  *(float4*)(out + (size_t)d*DD + gl*8)     = v0;
  *(float4*)(out + (size_t)d*DD + gl*8 + 4) = v1;
}

// ---- workspace layout (bytes) ---------------------------------------------
// xb     @ 0          : NN*DD*2 = 12,800,000
//   (aliased during prep: cur/deg @ 0 (1,600,000), blksum @ 1,600,000
//    (2,048) — both dead before k_conv writes xb)
// esrc   @ 12,800,000 : TE*4    = 6,400,000
// offs   @ 19,200,000 : (SS+1)*4 -> 1,600,016
// wb     @ 20,800,016 : 9*DD*DD*2 = 294,912        -> end 21,094,928
// xw     @ 21,095,168 : 9*NN*DD*2 = 115,200,000    -> end 136,295,168
extern "C" void kernel_launch(void* const* d_in, const int* in_sizes, int n_in,
                              void* d_out, int out_size, void* d_ws, size_t ws_size,
                              hipStream_t stream){
  const float* x  = (const float*)d_in[0];
  const float* w  = (const float*)d_in[1];
  const float* sw = (const float*)d_in[2];
  const int*   ei = (const int*)d_in[3];
  const int*   et = (const int*)d_in[4];
  float* out = (float*)d_out;
  char* ws = (char*)d_ws;

  if (ws_size < (size_t)136295168) return;   // big path proven available (R5)

  unsigned short* xb = (unsigned short*)(ws + 0);
  int*           cur = (int*)(ws + 0);               // alias (dead before xb)
  int*        blksum = (int*)(ws + 1600000);         // alias
  int*          esrc = (int*)(ws + 12800000);
  int*          offs = (int*)(ws + 19200000);
  unsigned short* wb = (unsigned short*)(ws + 20800016);
  unsigned short* xw = (unsigned short*)(ws + 21095168);

  hipMemsetAsync(cur, 0, (size_t)SS*4, stream);      // deg = 0
  k_deg  <<<2048, 256, 0, stream>>>(ei, et, cur);
  k_scan1<<<SCB, 256, 0, stream>>>(cur, offs, blksum);
  k_scan2<<<1, 512, 0, stream>>>(blksum, SCB);
  k_scan3<<<(SS + 255)/256, 256, 0, stream>>>(offs, cur, blksum);
  k_place<<<2048, 256, 0, stream>>>(ei, et, cur, esrc);
  k_conv <<<(NN*DD/4 + 9*DD*DD + 255)/256, 256, 0, stream>>>(x, w, sw, xb, wb);
  k_xw   <<<(NN + 127)/128, 256, 0, stream>>>(xb, wb, xw);
  k_agg  <<<NN/16, 256, 0, stream>>>(xw, offs, esrc, out);
}

// Round 7
// 241.486 us; speedup vs baseline: 1.5891x; 1.5891x over previous
//
#include <hip/hip_runtime.h>

#define NN 50000
#define EE 800000
#define RR 8
#define DD 128
#define SS (NN*RR)        // 400000 segments
#define TE (2*EE)         // 1600000 directed edges
#define NB 782            // dst buckets of 64 nodes
#define NBLK 391          // partition blocks, 4096 directed edges each
#define NS (NB*NBLK)      // 305762 scan elements
#define CONVB 6826        // ceil((NN*DD/4 + 9*DD*DD)/256)
#define XWB 391           // ceil(NN/128)

typedef __attribute__((ext_vector_type(8))) short bf16x8;
typedef __attribute__((ext_vector_type(4))) float f32x4;

__device__ __forceinline__ unsigned short f2bf(float f){
  unsigned int u = __float_as_uint(f);
  u += 0x7fffu + ((u >> 16) & 1u);   // round-to-nearest-even
  return (unsigned short)(u >> 16);
}
__device__ __forceinline__ float bf_lo(unsigned int w){ return __uint_as_float(w << 16); }
__device__ __forceinline__ float bf_hi(unsigned int w){ return __uint_as_float(w & 0xffff0000u); }

__device__ __forceinline__ void acc8(float* a, uint4 u){
  a[0] += bf_lo(u.x); a[1] += bf_hi(u.x);
  a[2] += bf_lo(u.y); a[3] += bf_hi(u.y);
  a[4] += bf_lo(u.z); a[5] += bf_hi(u.z);
  a[6] += bf_lo(u.w); a[7] += bf_hi(u.w);
}
__device__ __forceinline__ void acc8s(float* a, uint4 u, float s){
  a[0] += s*bf_lo(u.x); a[1] += s*bf_hi(u.x);
  a[2] += s*bf_lo(u.y); a[3] += s*bf_hi(u.y);
  a[4] += s*bf_lo(u.z); a[5] += s*bf_hi(u.z);
  a[6] += s*bf_lo(u.w); a[7] += s*bf_hi(u.w);
}

// directed edge j in [0,TE): j<EE forward (s->d), else reversed
__device__ __forceinline__ void dir_edge(const int* ei, const int* et, int j,
                                         int& s, int& d, int& t){
  if (j < EE){ s = ei[j]; d = ei[EE + j]; t = et[j]; }
  else { int jj = j - EE; s = ei[EE + jj]; d = ei[jj]; t = et[jj]; }
}

// ===========================================================================
// Launch 1: hist (391 blocks) || conv (6826 blocks) — independent chains
// ===========================================================================
__global__ __launch_bounds__(256) void k_histconv(
    const int* __restrict__ ei, const int* __restrict__ et,
    int* __restrict__ hist,
    const float* __restrict__ x, const float* __restrict__ w,
    const float* __restrict__ sw,
    unsigned short* __restrict__ xb, unsigned short* __restrict__ wb)
{
  __shared__ int h[NB];
  if (blockIdx.x < NBLK){
    // ---- per-(bucket,block) histogram (verbatim R5 k_hist) ----------------
    int tid = threadIdx.x, bid = blockIdx.x;
    for (int i = tid; i < NB; i += 256) h[i] = 0;
    __syncthreads();
    int j0 = bid*4096;
    for (int k = tid; k < 4096; k += 256){
      int j = j0 + k;
      if (j < TE){
        int s, d, t; dir_edge(ei, et, j, s, d, t);
        atomicAdd(&h[d >> 6], 1);           // LDS atomic
      }
    }
    __syncthreads();
    for (int i = tid; i < NB; i += 256) hist[i*NBLK + bid] = h[i];
  } else {
    // ---- conversions (verbatim R5 k_conv) ---------------------------------
    int i = (blockIdx.x - NBLK)*256 + threadIdx.x;
    const int M1 = NN*DD/4;            // 1,600,000 float4 groups
    if (i < M1){
      float4 v = ((const float4*)x)[i];
      ushort4 o;
      o.x = f2bf(v.x); o.y = f2bf(v.y); o.z = f2bf(v.z); o.w = f2bf(v.w);
      ((ushort4*)xb)[i] = o;
    } else {
      int j = i - M1;
      if (j < 9*DD*DD){
        int r = j >> 14; int rem = j & 16383; int n = rem >> 7; int k = rem & 127;
        float v = (r < 8) ? w[r*16384 + k*128 + n] : sw[k*128 + n];
        wb[j] = f2bf(v);
      }
    }
  }
}

// ---- scan over NS elements (in-place exclusive), 3 kernels (R5 verbatim) --
__global__ __launch_bounds__(256) void k_scan1(int* __restrict__ hist,
                                               int* __restrict__ blksum){
  __shared__ int sd[256];
  int b = blockIdx.x, tid = threadIdx.x;
  int base = b*1024 + tid*4;
  int v0 = (base+0 < NS) ? hist[base+0] : 0;
  int v1 = (base+1 < NS) ? hist[base+1] : 0;
  int v2 = (base+2 < NS) ? hist[base+2] : 0;
  int v3 = (base+3 < NS) ? hist[base+3] : 0;
  int ts = v0+v1+v2+v3;
  sd[tid] = ts; __syncthreads();
  for (int o = 1; o < 256; o <<= 1){
    int t = (tid >= o) ? sd[tid-o] : 0;
    __syncthreads();
    sd[tid] += t;
    __syncthreads();
  }
  int ex = sd[tid] - ts;
  if (base+0 < NS) hist[base+0] = ex; ex += v0;
  if (base+1 < NS) hist[base+1] = ex; ex += v1;
  if (base+2 < NS) hist[base+2] = ex; ex += v2;
  if (base+3 < NS) hist[base+3] = ex;
  if (tid == 255) blksum[b] = sd[255];
}

__global__ __launch_bounds__(512) void k_scan2(int* __restrict__ blksum, int nb){
  __shared__ int sd[512];
  int tid = threadIdx.x;
  int v = (tid < nb) ? blksum[tid] : 0;
  sd[tid] = v; __syncthreads();
  for (int o = 1; o < 512; o <<= 1){
    int t = (tid >= o) ? sd[tid-o] : 0;
    __syncthreads();
    sd[tid] += t;
    __syncthreads();
  }
  if (tid < nb) blksum[tid] = sd[tid] - v;   // exclusive
}

__global__ __launch_bounds__(256) void k_scan3(int* __restrict__ hist,
                                               const int* __restrict__ blksum){
  int i = blockIdx.x*blockDim.x + threadIdx.x;
  if (i < NS) hist[i] += blksum[i >> 10];
}

// ===========================================================================
// Launch 5: part (391 blocks) || xw (391 blocks) — independent chains.
// Shared-memory union: part uses first 3128 B as cur[NB]; xw uses 64 KiB Bs.
// ===========================================================================
__global__ __launch_bounds__(256, 2) void k_partxw(
    const int* __restrict__ ei, const int* __restrict__ et,
    const int* __restrict__ S, unsigned int* __restrict__ P,
    const unsigned short* __restrict__ xb,
    const unsigned short* __restrict__ wb,
    unsigned short* __restrict__ xw)
{
  __shared__ __align__(16) unsigned short Bs[2][16384];   // 64 KiB union
  if (blockIdx.x < NBLK){
    // ---- partition: place packed edges into bucket slices (R5 k_part) ----
    // packed: src (17b) | dstlo (6b @17) | rel (3b @23)
    int* cur = (int*)&Bs[0][0];
    int tid = threadIdx.x, bid = blockIdx.x;
    for (int i = tid; i < NB; i += 256) cur[i] = S[i*NBLK + bid];
    __syncthreads();
    int j0 = bid*4096;
    for (int k = tid; k < 4096; k += 256){
      int j = j0 + k;
      if (j < TE){
        int s, d, t; dir_edge(ei, et, j, s, d, t);
        int b = d >> 6;
        int p = atomicAdd(&cur[b], 1);       // LDS atomic rank
        P[p] = (unsigned int)s | ((unsigned int)(d & 63) << 17)
             | ((unsigned int)t << 23);
      }
    }
  } else {
    // ---- xw[r] = xb @ W_r, r=0..8 (R6 k_xw body, bid rebased) -------------
    const int bid  = blockIdx.x - NBLK;
    const int tid  = threadIdx.x;
    const int wave = tid >> 6, lane = tid & 63;
    const int l15  = lane & 15, quad = lane >> 4;
    const int row0 = bid * 128 + wave * 32;

    bf16x8 af[2][4];
    #pragma unroll
    for (int m = 0; m < 2; ++m){
      int gr = row0 + m*16 + l15; if (gr >= NN) gr = NN - 1;
      #pragma unroll
      for (int ks = 0; ks < 4; ++ks)
        af[m][ks] = *(const bf16x8*)(xb + (size_t)gr*DD + ks*32 + quad*8);
    }

    auto stage = [&](int r, int b){
      #pragma unroll
      for (int j = 0; j < 8; ++j){
        int n = j*16 + wave*4 + (lane >> 4);       // B row 0..127
        int c = lane & 15;                         // 16B chunk within row
        const unsigned short* gp = wb + r*16384 + n*128 + ((c ^ (n & 7)) << 3);
        __builtin_amdgcn_global_load_lds(
            (const __attribute__((address_space(1))) void*)gp,
            (__attribute__((address_space(3))) void*)((char*)&Bs[b][0] + j*4096 + wave*1024),
            16, 0, 0);
      }
    };

    stage(0, 0);

    #pragma unroll 1
    for (int r = 0; r < 9; ++r){
      __syncthreads();                   // stage(r) complete
      if (r < 8) stage(r + 1, (r + 1) & 1);

      f32x4 C[2][8];
      #pragma unroll
      for (int m = 0; m < 2; ++m)
        #pragma unroll
        for (int nt = 0; nt < 8; ++nt) C[m][nt] = (f32x4)(0.f);

      const char* bb = (const char*)&Bs[r & 1][0];
      #pragma unroll
      for (int nt = 0; nt < 8; ++nt){
        bf16x8 bf[4];
        #pragma unroll
        for (int ks = 0; ks < 4; ++ks)
          bf[ks] = *(const bf16x8*)(bb + (nt*16 + l15)*256
                                       + (((ks*4 + quad) ^ (l15 & 7)) << 4));
        #pragma unroll
        for (int ks = 0; ks < 4; ++ks){
          C[0][nt] = __builtin_amdgcn_mfma_f32_16x16x32_bf16(af[0][ks], bf[ks], C[0][nt], 0, 0, 0);
          C[1][nt] = __builtin_amdgcn_mfma_f32_16x16x32_bf16(af[1][ks], bf[ks], C[1][nt], 0, 0, 0);
        }
      }

      unsigned short* xs = xw + (size_t)r * NN * DD;
      #pragma unroll
      for (int m = 0; m < 2; ++m)
        #pragma unroll
        for (int nt = 0; nt < 8; ++nt)
          #pragma unroll
          for (int i = 0; i < 4; ++i){
            int gr = row0 + m*16 + quad*4 + i;
            if (gr < NN) xs[(size_t)gr*DD + nt*16 + l15] = f2bf(C[m][nt][i]);
          }
    }
  }
}

// ---- phase B: per-bucket counting sort -> offs + esrc (R5 verbatim) -------
// esrc entries are packed: src (17b) | rel (3b @17)
__global__ __launch_bounds__(256) void k_build(const unsigned int* __restrict__ P,
                                               const int* __restrict__ S,
                                               int* __restrict__ esrc,
                                               int* __restrict__ offs){
  __shared__ int h[512], cu[512], sd[256];
  int tid = threadIdx.x, b = blockIdx.x;
  int pstart = S[b*NBLK];
  int pend   = (b+1 < NB) ? S[(b+1)*NBLK] : TE;
  int ne = pend - pstart;
  h[2*tid] = 0; h[2*tid+1] = 0;
  __syncthreads();
  for (int k = tid; k < ne; k += 256){
    unsigned int u = P[pstart + k];
    int lseg = (int)(((u >> 17) & 63u)*8u + (u >> 23));
    atomicAdd(&h[lseg], 1);                // LDS atomic
  }
  __syncthreads();
  // exclusive scan of 512 bins with 256 threads
  int v0 = h[2*tid], v1 = h[2*tid+1];
  int ts = v0 + v1;
  sd[tid] = ts; __syncthreads();
  for (int o = 1; o < 256; o <<= 1){
    int t = (tid >= o) ? sd[tid-o] : 0;
    __syncthreads();
    sd[tid] += t;
    __syncthreads();
  }
  int ex = sd[tid] - ts;
  cu[2*tid]   = pstart + ex;
  cu[2*tid+1] = pstart + ex + v0;
  int seg0 = b*512;
  if (seg0 + 2*tid     < SS) offs[seg0 + 2*tid]     = cu[2*tid];
  if (seg0 + 2*tid + 1 < SS) offs[seg0 + 2*tid + 1] = cu[2*tid+1];
  if (b == NB-1 && tid == 0) offs[SS] = TE;
  __syncthreads();
  for (int k = tid; k < ne; k += 256){
    unsigned int u = P[pstart + k];
    int lseg = (int)(((u >> 17) & 63u)*8u + (u >> 23));
    int r = atomicAdd(&cu[lseg], 1);       // LDS atomic
    esrc[r] = (int)(u & 0x1ffffu) | (int)(((u >> 23) & 7u) << 17);
  }
}

// ===========================================================================
// k_agg: out[d] = sum_edges (1/deg_seg)*xw[rel][src] + xw[8][d] (R6 verbatim)
// ===========================================================================
__global__ __launch_bounds__(256, 4) void k_agg(
    const unsigned short* __restrict__ xw,
    const int* __restrict__ offs,
    const int* __restrict__ esrc,
    float* __restrict__ out)
{
  const int tid   = threadIdx.x;
  const int lane  = tid & 63;
  const int gl    = lane & 15;
  const int basel = lane & 48;               // group base lane within wave
  const int d     = blockIdx.x * 16 + (tid >> 4);   // NN = 3125*16 exact

  int o = 0;
  if (gl < 9) o = offs[d*8 + gl];
  int onx = __shfl(o, (basel + gl + 1) & 63);       // valid for gl<8
  int cnt = onx - o;
  float scale = (gl < 8 && cnt > 0) ? 1.0f/(float)cnt : 0.0f;
  int ebase = __shfl(o, basel);
  int etot  = __shfl(o, basel + 8) - ebase;

  float a[8] = {0.f,0.f,0.f,0.f,0.f,0.f,0.f,0.f};

  int pk[8];
  #pragma unroll
  for (int s = 0; s < 8; ++s) pk[s] = (s < etot) ? esrc[ebase + s] : 0;

  for (int e = 0; e < etot; e += 8){
    uint4 U[8]; float sc[8];
    #pragma unroll
    for (int s = 0; s < 8; ++s){
      sc[s] = 0.f;
      U[s] = make_uint4(0u,0u,0u,0u);
      if (e + s < etot){
        int rel = (pk[s] >> 17) & 7;
        sc[s]   = __shfl(scale, basel + rel);
        int src = pk[s] & 0x1ffff;
        U[s] = *(const uint4*)(xw + ((size_t)rel*NN + src)*DD + gl*8);
      }
    }
    #pragma unroll
    for (int s = 0; s < 8; ++s){              // prefetch next batch's records
      int en = e + 8 + s;
      pk[s] = (en < etot) ? esrc[ebase + en] : 0;
    }
    #pragma unroll
    for (int s = 0; s < 8; ++s) acc8s(a, U[s], sc[s]);
  }

  // self row (slab 8), scale 1
  {
    uint4 u = *(const uint4*)(xw + ((size_t)8*NN + d)*DD + gl*8);
    acc8(a, u);
  }

  float4 v0; v0.x = a[0]; v0.y = a[1]; v0.z = a[2]; v0.w = a[3];
  float4 v1; v1.x = a[4]; v1.y = a[5]; v1.z = a[6]; v1.w = a[7];
  *(float4*)(out + (size_t)d*DD + gl*8)     = v0;
  *(float4*)(out + (size_t)d*DD + gl*8 + 4) = v1;
}

// ---- memory layout --------------------------------------------------------
// ws:  xb   @ 0          : NN*DD*2 = 12,800,000
//      esrc @ 12,800,000 : TE*4    = 6,400,000
//      offs @ 19,200,000 : (SS+1)*4 -> 1,600,016
//      wb   @ 20,800,016 : 9*DD*DD*2 = 294,912     -> end 21,094,928
//      xw   @ 21,095,168 : 9*NN*DD*2 = 115,200,000 -> end 136,295,168
// out (25.6 MB) doubles as prep scratch, all dead before k_agg writes out:
//      P      @ out+0         : TE*4 = 6,400,000
//      hist   @ out+6,400,000 : NS*4 = 1,223,048
//      blksum @ out+7,623,168 : 1,196
extern "C" void kernel_launch(void* const* d_in, const int* in_sizes, int n_in,
                              void* d_out, int out_size, void* d_ws, size_t ws_size,
                              hipStream_t stream){
  const float* x  = (const float*)d_in[0];
  const float* w  = (const float*)d_in[1];
  const float* sw = (const float*)d_in[2];
  const int*   ei = (const int*)d_in[3];
  const int*   et = (const int*)d_in[4];
  float* out = (float*)d_out;
  char* ws = (char*)d_ws;

  if (ws_size < (size_t)136295168) return;   // big path proven available (R6)

  unsigned short* xb = (unsigned short*)(ws + 0);
  int*          esrc = (int*)(ws + 12800000);
  int*          offs = (int*)(ws + 19200000);
  unsigned short* wb = (unsigned short*)(ws + 20800016);
  unsigned short* xw = (unsigned short*)(ws + 21095168);

  unsigned int*    P = (unsigned int*)((char*)d_out + 0);
  int*          hist = (int*)((char*)d_out + 6400000);
  int*        blksum = (int*)((char*)d_out + 7623168);

  k_histconv<<<NBLK + CONVB, 256, 0, stream>>>(ei, et, hist, x, w, sw, xb, wb);
  k_scan1<<<(NS + 1023)/1024, 256, 0, stream>>>(hist, blksum);   // 299 blocks
  k_scan2<<<1, 512, 0, stream>>>(blksum, (NS + 1023)/1024);
  k_scan3<<<(NS + 255)/256, 256, 0, stream>>>(hist, blksum);
  k_partxw<<<NBLK + XWB, 256, 0, stream>>>(ei, et, hist, P, xb, wb, xw);
  k_build<<<NB, 256, 0, stream>>>(P, hist, esrc, offs);
  k_agg<<<NN/16, 256, 0, stream>>>(xw, offs, esrc, out);
}